// Round 2
// baseline (723.498 us; speedup 1.0000x reference)
//
#include <hip/hip_runtime.h>

// Problem constants
#define HDIM 256
#define WDIM 256
#define DDIM 64
#define HWSZ (HDIM*WDIM)          // 65536
#define NPIX 524288               // 8 * 65536

// Tiling: 32 wide x 8 tall tile, 256 threads = 4 waves.
// Each WAVE owns 2 output rows and stages its OWN 8-row x 38-col vis halo
// into a private LDS region -> ZERO barriers in the d-loop (DS ops are
// in-order per wave). Waves free-run; LDS/VALU/VMEM phases of different
// waves overlap instead of lock-stepping on 16 block-wide barriers.
#define TW 32
#define TH 8
#define BT 256
#define NW 4                      // waves per block
#define RR 38                     // region cols = TW+6
#define RH 8                      // region rows = 2+6
#define RPX 304                   // RR*RH halo px per wave
#define NST 5                     // ceil(304/64) stages per lane
#define RSTR 4                    // floats per px (8 packed f16 = 16 B)
#define DC 8                      // d-chunk size
#define NCH 8                     // 64/DC

typedef _Float16 f16;
typedef __attribute__((ext_vector_type(2))) _Float16 f16x2;

#if defined(__has_builtin)
# if __has_builtin(__builtin_amdgcn_fdot2)
#  define HAVE_FDOT2 1
# endif
#endif

__device__ __forceinline__ float fdot2(f16x2 a, f16x2 b, float c) {
#ifdef HAVE_FDOT2
    return __builtin_amdgcn_fdot2(a, b, c, false);   // v_dot2_f32_f16
#else
    return c + (float)a.x * (float)b.x + (float)a.y * (float)b.y;
#endif
}

__device__ __forceinline__ float pk2(float a, float b) {   // pack 2 fp32 -> f16x2 bits (RNE)
    f16x2 t; t.x = (f16)a; t.y = (f16)b;
    return __builtin_bit_cast(float, t);
}

__device__ __forceinline__ f16x2 bc(float x) {
    return __builtin_bit_cast(f16x2, x);
}

// d_out layout (floats): dy, dx, conf_local, conf_global, local_weight, logits
#define OFF_DY   0
#define OFF_DX   524288
#define OFF_CONF 1048576
#define OFF_CG   1572864
#define OFF_LW   1572872
#define OFF_LG   2097160

// workspace layout (floats)
#define WS_GACC 0                 // 8*49 logit sums
#define WS_DYG  392
#define WS_DXG  400

__global__ void zero_ws_k(float* __restrict__ ws) {
    const int i = threadIdx.x;
    if (i < 408) ws[i] = 0.f;
}

__global__ void __launch_bounds__(BT, 4)
corr_main_k(const float* __restrict__ rub, const float* __restrict__ vis,
            const float* __restrict__ ltemp, float* __restrict__ out,
            float* __restrict__ ws)
{
    // Per-wave private regions; 16 B px stride -> b128 reads/writes hit all
    // 32 banks once per 8 lanes (conflict-free).
    __shared__ __align__(16) float vis_s[NW * RPX * RSTR];   // 19456 B
    __shared__ float invv_s[NW * RPX];                       // 4864 B
    __shared__ float gacc_s[49];

    const int tid  = threadIdx.x;
    const int wv   = tid >> 6;                // wave 0..3
    const int lane = tid & 63;
    const int hl   = lane >> 5;               // row within wave pair
    const int tx   = lane & 31;
    const int ty   = 2 * wv + hl;             // 0..7
    const int w0 = blockIdx.x * TW;
    const int h0 = blockIdx.y * TH;
    const int b  = blockIdx.z;
    const int ibase = b * (DDIM * HWSZ);

    if (tid < 49) gacc_s[tid] = 0.f;

    // This lane's staged halo pixels: p = lane + 64*j (clamped dup benign:
    // clamped lanes recompute/rewrite identical data for px RPX-1).
    int gso[NST], ivof[NST];
#pragma unroll
    for (int j = 0; j < NST; ++j) {
        int p = lane + 64 * j; if (p > RPX - 1) p = RPX - 1;
        const int row = p / RR;
        const int col = p - row * RR;
        const int gh = min(HDIM - 1, max(0, h0 + 2 * wv - 3 + row));  // edge pad
        const int gw = min(WDIM - 1, max(0, w0 - 3 + col));
        gso[j]  = gh * WDIM + gw;
        ivof[j] = wv * RPX + p;
    }
    const int pown = (h0 + ty) * WDIM + (w0 + tx);

    float acc[49];
#pragma unroll
    for (int k = 0; k < 49; ++k) acc[k] = 0.f;
    float sqa[NST] = {0.f, 0.f, 0.f, 0.f, 0.f};
    float sr = 0.f;

    // Register pipeline: vv/rn hold chunk c at iter-c top (issued iter c-1,
    // a full compute phase to land -> vmcnt wait ~0 at pack time).
    float vv[NST][DC], rn[DC];
#pragma unroll
    for (int j = 0; j < NST; ++j)
#pragma unroll
        for (int d = 0; d < DC; ++d) vv[j][d] = vis[ibase + d * HWSZ + gso[j]];
#pragma unroll
    for (int d = 0; d < DC; ++d) rn[d] = rub[ibase + d * HWSZ + pown];

    const float* vb = &vis_s[(wv * RPX + hl * RR + tx) * RSTR];
    const float* ib = &invv_s[wv * RPX + hl * RR + tx];
    f16x2 rh[4];

#pragma unroll 1
    for (int c = 0; c < NCH; ++c) {
        // Pack + write chunk c into this wave's region (no barrier: region is
        // wave-private; prior chunk's reads precede these writes in the
        // wave's in-order DS stream).
#pragma unroll
        for (int j = 0; j < NST; ++j) {
            *reinterpret_cast<float4*>(&vis_s[ivof[j] * RSTR]) =
                make_float4(pk2(vv[j][0], vv[j][1]), pk2(vv[j][2], vv[j][3]),
                            pk2(vv[j][4], vv[j][5]), pk2(vv[j][6], vv[j][7]));
#pragma unroll
            for (int d = 0; d < DC; ++d) sqa[j] = fmaf(vv[j][d], vv[j][d], sqa[j]);
        }
#pragma unroll
        for (int jj = 0; jj < 4; ++jj) {
            f16x2 t; t.x = (f16)rn[2*jj]; t.y = (f16)rn[2*jj+1]; rh[jj] = t;
        }
#pragma unroll
        for (int d = 0; d < DC; ++d) sr = fmaf(rn[d], rn[d], sr);

        if (c + 1 < NCH) {                    // issue chunk c+1 (lands during compute)
#pragma unroll
            for (int j = 0; j < NST; ++j)
#pragma unroll
                for (int d = 0; d < DC; ++d)
                    vv[j][d] = vis[ibase + ((c + 1) * DC + d) * HWSZ + gso[j]];
#pragma unroll
            for (int d = 0; d < DC; ++d)
                rn[d] = rub[ibase + ((c + 1) * DC + d) * HWSZ + pown];
        }

        // 49 ds_read_b128 + 196 v_dot2_f32_f16; offsets compile-time imm
#pragma unroll
        for (int dyi = 0; dyi < 7; ++dyi) {
#pragma unroll
            for (int dxi = 0; dxi < 7; ++dxi) {
                const float4 v = *reinterpret_cast<const float4*>(
                    vb + (dyi * RR + dxi) * RSTR);
                float a = acc[dyi * 7 + dxi];
                a = fdot2(rh[0], bc(v.x), a);
                a = fdot2(rh[1], bc(v.y), a);
                a = fdot2(rh[2], bc(v.z), a);
                a = fdot2(rh[3], bc(v.w), a);
                acc[dyi * 7 + dxi] = a;
            }
        }
    }

    // Publish inverse vis norms to the wave-private region (same-wave DS
    // in-order; reads below are from this wave only -> no barrier).
#pragma unroll
    for (int j = 0; j < NST; ++j)
        invv_s[ivof[j]] = 1.f / fmaxf(sqrtf(sqa[j]), 1e-6f);

    const float tau  = fmaxf(__expf(ltemp[0]), 1e-3f);
    const float itau = 1.f / tau;
    const float invr = 1.f / fmaxf(sqrtf(sr), 1e-6f);
    const float cR   = invr * 0.125f;          // scale = 1/sqrt(64)
    const float uu   = 1.f / 49.f;
    const float i1mu = 49.f / 48.f;

    const int h = h0 + ty, w = w0 + tx;
    const int lgbase = OFF_LG + b * 49 * HWSZ + h * WDIM + w;
    float mlg = -1e30f;
#pragma unroll
    for (int dyi = 0; dyi < 7; ++dyi) {
#pragma unroll
        for (int dxi = 0; dxi < 7; ++dxi) {
            const int k = dyi * 7 + dxi;
            const float lg = acc[k] * cR * ib[dyi * RR + dxi];
            out[lgbase + k * HWSZ] = lg;
            acc[k] = lg;                       // keep logit for global reduction
            mlg = fmaxf(mlg, lg);
        }
    }
    const float m = mlg * itau;
    float S = 0.f, sdy = 0.f, sdx = 0.f;
#pragma unroll
    for (int dyi = 0; dyi < 7; ++dyi) {
#pragma unroll
        for (int dxi = 0; dxi < 7; ++dxi) {
            const float e = __expf(fmaf(acc[dyi * 7 + dxi], itau, -m));
            S += e;
            sdy += e * (float)(dyi - 3);
            sdx += e * (float)(dxi - 3);
        }
    }
    const float invS = 1.f / S;
    const float conf = invS;                   // max prob = exp(0)/S
    const float lw   = fminf(fmaxf((conf - uu) * i1mu, 0.f), 1.f);
    const int po = b * HWSZ + h * WDIM + w;
    out[OFF_CONF + po] = conf;
    out[OFF_LW   + po] = lw;
    out[OFF_DY   + po] = sdy * invS;           // local; combine_k blends with global
    out[OFF_DX   + po] = sdx * invS;

    // Global branch: wave butterfly -> LDS atomic -> one global atomic per block.
    // First barrier also guarantees gacc_s zero-init is visible.
#pragma unroll
    for (int k = 0; k < 49; ++k) {
        float v = acc[k];
#pragma unroll
        for (int off = 32; off > 0; off >>= 1)
            v += __shfl_xor(v, off, 64);
        acc[k] = v;                            // lane0 holds wave sum
    }
    __syncthreads();
    if ((tid & 63) == 0) {
#pragma unroll
        for (int k = 0; k < 49; ++k) atomicAdd(&gacc_s[k], acc[k]);
    }
    __syncthreads();
    if (tid < 49) atomicAdd(&ws[WS_GACC + b * 49 + tid], gacc_s[tid]);
}

__global__ void glob_branch_k(const float* __restrict__ ltemp,
                              float* __restrict__ out, float* __restrict__ ws)
{
    const int t = threadIdx.x;
    if (t >= 8) return;
    const float tau  = fmaxf(__expf(ltemp[0]), 1e-3f);
    const float itau = 1.f / tau;
    float tk[49];
    float m = -1e30f;
#pragma unroll
    for (int k = 0; k < 49; ++k) {
        const float mean = ws[WS_GACC + t * 49 + k] * (1.f / 65536.f);
        tk[k] = mean * itau;
        m = fmaxf(m, tk[k]);
    }
    float S = 0.f, sdy = 0.f, sdx = 0.f;
#pragma unroll
    for (int k = 0; k < 49; ++k) {
        const float e = __expf(tk[k] - m);
        S += e;
        sdy += e * (float)(k / 7 - 3);
        sdx += e * (float)(k % 7 - 3);
    }
    const float invS = 1.f / S;
    out[OFF_CG + t] = invS;                  // conf_global
    ws[WS_DYG + t] = sdy * invS;
    ws[WS_DXG + t] = sdx * invS;
}

__global__ void combine_k(float* __restrict__ out, const float* __restrict__ ws)
{
    const int gid = blockIdx.x * 256 + threadIdx.x;
    if (gid >= NPIX) return;
    const int b = gid >> 16;
    const float lw  = out[OFF_LW + gid];
    const float dyl = out[OFF_DY + gid];
    const float dxl = out[OFF_DX + gid];
    out[OFF_DY + gid] = lw * dyl + (1.f - lw) * ws[WS_DYG + b];
    out[OFF_DX + gid] = lw * dxl + (1.f - lw) * ws[WS_DXG + b];
}

extern "C" void kernel_launch(void* const* d_in, const int* in_sizes, int n_in,
                              void* d_out, int out_size, void* d_ws, size_t ws_size,
                              hipStream_t stream)
{
    const float* rub = (const float*)d_in[0];
    const float* vis = (const float*)d_in[1];
    const float* lt  = (const float*)d_in[2];
    float* out = (float*)d_out;
    float* ws  = (float*)d_ws;

    hipLaunchKernelGGL(zero_ws_k, dim3(1), dim3(512), 0, stream, ws);
    hipLaunchKernelGGL(corr_main_k, dim3(WDIM / TW, HDIM / TH, 8), dim3(BT), 0, stream,
                       rub, vis, lt, out, ws);
    hipLaunchKernelGGL(glob_branch_k, dim3(1), dim3(64), 0, stream, lt, out, ws);
    hipLaunchKernelGGL(combine_k, dim3(NPIX / 256), dim3(256), 0, stream, out, ws);
}

// Round 3
// 429.985 us; speedup vs baseline: 1.6826x; 1.6826x over previous
//
#include <hip/hip_runtime.h>

// Problem constants
#define HDIM 256
#define WDIM 256
#define DDIM 64
#define HWSZ (HDIM*WDIM)          // 65536
#define NPIX 524288               // 8 * 65536

// MFMA band-GEMM structure: 32x16 px tile, 512 threads = 8 waves.
// Each wave owns 4 row-strips of 16 px (2 strip-cols x 16 rows per block).
// Per strip: A = 16 rubin px x 32 d (f16), B = vis halo px x 32 d from LDS,
// C[i][n] = dot(rub_i, vis_n); taps are diagonals t = n-i in [0,6], covered
// by two B tiles (n, n+16). Full 64-d vis halo staged ONCE as f16 -> one
// barrier total; waves free-run through compute (no lockstep).
#define TW 32
#define TH 16
#define BT 512
#define HR 22                     // halo rows = TH+6
#define HC 38                     // halo cols = TW+6
#define NHP 836                   // HR*HC halo pixels
#define PXF4 9                    // float4 slots per halo px (8 d-blocks + pad)
                                  // 144 B stride: bank rotation 4/px -> 2-way max (free)

// d_out layout (floats): dy, dx, conf_local, conf_global, local_weight, logits
#define OFF_DY   0
#define OFF_DX   524288
#define OFF_CONF 1048576
#define OFF_CG   1572864
#define OFF_LW   1572872
#define OFF_LG   2097160

// workspace layout (floats)
#define WS_GACC 0                 // 8*49 logit sums
#define WS_DYG  392
#define WS_DXG  400

typedef _Float16 f16;
typedef __attribute__((ext_vector_type(8))) _Float16 f16x8;
typedef __attribute__((ext_vector_type(4))) float f32x4;

__device__ __forceinline__ float pk2(float a, float b) {   // 2 fp32 -> f16x2 bits (RNE)
    union { f16 h[2]; float f; } u;
    u.h[0] = (f16)a; u.h[1] = (f16)b;
    return u.f;
}

__global__ void zero_ws_k(float* __restrict__ ws) {
    const int i = threadIdx.x;
    if (i < 408) ws[i] = 0.f;
}

__global__ void __launch_bounds__(BT, 2)
corr_main_k(const float* __restrict__ rub, const float* __restrict__ vis,
            const float* __restrict__ ltemp, float* __restrict__ out,
            float* __restrict__ ws)
{
    __shared__ __align__(16) float vis_s[NHP * 36];   // 120384 B: 64 f16 + pad per px
    __shared__ float invv_s[NHP];                     // 3344 B
    __shared__ float tb[8 * 16 * 52];                 // 26624 B: per-wave transpose buf
    __shared__ float gacc_s[49];

    const int tid  = threadIdx.x;
    const int wv   = tid >> 6;                // wave 0..7
    const int lane = tid & 63;
    const int g    = lane >> 4;               // 0..3 (k-block / C row-group)
    const int n    = lane & 15;               // 0..15 (C col / A row)
    const int w0 = blockIdx.x * TW;
    const int h0 = blockIdx.y * TH;
    const int b  = blockIdx.z;
    const int ibase = b * (DDIM * HWSZ);

    if (tid < 49) gacc_s[tid] = 0.f;

    // ---- Stage full 64-d vis halo as f16 (one pass), plus per-px inv norm ----
#pragma unroll
    for (int rep = 0; rep < 2; ++rep) {
        const int p = tid + rep * BT;
        if (p < NHP) {
            const int hr = p / HC, wc = p - hr * HC;
            const int gof = min(HDIM-1, max(0, h0-3+hr)) * WDIM
                          + min(WDIM-1, max(0, w0-3+wc));       // edge-replicate
            float v[64];
#pragma unroll
            for (int d = 0; d < 64; ++d) v[d] = vis[ibase + d * HWSZ + gof];
            float ssq = 0.f;
#pragma unroll
            for (int d = 0; d < 64; ++d) ssq = fmaf(v[d], v[d], ssq);
#pragma unroll
            for (int blk = 0; blk < 8; ++blk)
                reinterpret_cast<float4*>(vis_s)[p * PXF4 + blk] =
                    make_float4(pk2(v[blk*8+0], v[blk*8+1]), pk2(v[blk*8+2], v[blk*8+3]),
                                pk2(v[blk*8+4], v[blk*8+5]), pk2(v[blk*8+6], v[blk*8+7]));
            invv_s[p] = 1.f / fmaxf(sqrtf(ssq), 1e-6f);
        }
    }

    // ---- Prefetch this wave's 4 strips of rubin (A operands), f32 ----
    // Lane holds A[row=n][k-slot (g,j)]: d = kc*32 + g*8 + j  (k-map identical
    // for A and B -> any hw k-permutation cancels in the dot).
    const int sc   = wv >> 2;                 // strip column 0/1
    const int wrow = wv & 3;                  // wave row group
    const int wgx  = w0 + sc * 16 + n;
    float ar[4][16];
#pragma unroll
    for (int s = 0; s < 4; ++s) {
        const int h = h0 + wrow * 4 + s;
        const int base = ibase + h * WDIM + wgx + g * 8 * HWSZ;
#pragma unroll
        for (int j = 0; j < 8; ++j) {
            ar[s][j]     = rub[base + j * HWSZ];
            ar[s][8 + j] = rub[base + (32 + j) * HWSZ];
        }
    }

    __syncthreads();                          // the ONLY pre-compute barrier

    const float tau  = fmaxf(__expf(ltemp[0]), 1e-3f);
    const float itau = 1.f / tau;
    float tk[13];
#pragma unroll
    for (int m = 0; m < 13; ++m) tk[m] = 0.f;

    const f16x8* vp = reinterpret_cast<const f16x8*>(vis_s);
    float* tbw = &tb[wv * (16 * 52)];
    const f32x4 zz = {0.f, 0.f, 0.f, 0.f};

#pragma unroll 1
    for (int s = 0; s < 4; ++s) {
        const int ly = wrow * 4 + s;
        const int h  = h0 + ly;

        f16x8 ha0, ha1;
#pragma unroll
        for (int j = 0; j < 8; ++j) { ha0[j] = (f16)ar[s][j]; ha1[j] = (f16)ar[s][8+j]; }
        float ssqa = 0.f;
#pragma unroll
        for (int j = 0; j < 16; ++j) ssqa = fmaf(ar[s][j], ar[s][j], ssqa);
        ssqa += __shfl_xor(ssqa, 16, 64);
        ssqa += __shfl_xor(ssqa, 32, 64);     // now = full 64-d ssq of rubin px n
        const float sA = 0.125f / fmaxf(sqrtf(ssqa), 1e-6f);

        const int kap = n - 4 * g;            // n - (row-group base)
#pragma unroll
        for (int dyi = 0; dyi < 7; ++dyi) {
            const int row = ly + dyi;
            const int c0  = sc * 16 + n;                  // B tile0 halo col
            const int c1  = min(37, sc * 16 + 16 + n);    // tile1 (clamp = don't-care)
            const int p0  = (row * HC + c0) * PXF4;
            const int p1  = (row * HC + c1) * PXF4;
            f32x4 a0 = zz, a1 = zz;
            a0 = __builtin_amdgcn_mfma_f32_16x16x32_f16(ha0, vp[p0 + g],     a0, 0, 0, 0);
            a0 = __builtin_amdgcn_mfma_f32_16x16x32_f16(ha1, vp[p0 + 4 + g], a0, 0, 0, 0);
            a1 = __builtin_amdgcn_mfma_f32_16x16x32_f16(ha0, vp[p1 + g],     a1, 0, 0, 0);
            a1 = __builtin_amdgcn_mfma_f32_16x16x32_f16(ha1, vp[p1 + 4 + g], a1, 0, 0, 0);
            // C[i=4g+r][n]: tap t = n - i (+16 for tile1); scale by vis invnorm,
            // scatter into per-wave [px][tap] transpose buffer (wave-private).
            const float iv0 = invv_s[row * HC + c0];
            const float iv1 = invv_s[row * HC + c1];
            const int kb = dyi * 7;
#pragma unroll
            for (int r = 0; r < 4; ++r) {
                const int t0 = kap - r;
                if ((unsigned)t0 <= 6u) tbw[(4*g + r) * 52 + kb + t0] = a0[r] * iv0;
                const int t1 = kap - r + 16;
                if ((unsigned)t1 <= 6u) tbw[(4*g + r) * 52 + kb + t1] = a1[r] * iv1;
            }
        }

        // ---- Read back px-major (lane owns px=n, subtaps k = g+4m), finish ----
        float lgv[13];
        float M = -1e30f;
#pragma unroll
        for (int m = 0; m < 13; ++m) {
            const int k = g + 4 * m;
            if (k < 49) {
                const float lg = tbw[n * 52 + k] * sA;   // rubin invnorm * 0.125
                lgv[m] = lg;
                out[OFF_LG + b * (49 * HWSZ) + k * HWSZ + h * WDIM + w0 + sc*16 + n] = lg;
                tk[m] += lg;
                M = fmaxf(M, lg);
            }
        }
        M = fmaxf(M, __shfl_xor(M, 16, 64));
        M = fmaxf(M, __shfl_xor(M, 32, 64));
        const float mm = M * itau;
        float S = 0.f, sdy = 0.f, sdx = 0.f;
#pragma unroll
        for (int m = 0; m < 13; ++m) {
            const int k = g + 4 * m;
            if (k < 49) {
                const float e = __expf(fmaf(lgv[m], itau, -mm));
                const int dyk = (k * 37) >> 8;            // == k/7 for k<49
                const int dxk = k - dyk * 7;
                S += e; sdy += e * (float)(dyk - 3); sdx += e * (float)(dxk - 3);
            }
        }
        S   += __shfl_xor(S, 16, 64);   S   += __shfl_xor(S, 32, 64);
        sdy += __shfl_xor(sdy, 16, 64); sdy += __shfl_xor(sdy, 32, 64);
        sdx += __shfl_xor(sdx, 16, 64); sdx += __shfl_xor(sdx, 32, 64);
        if (g == 0) {
            const float invS = 1.f / S;
            const float conf = invS;                       // max prob = exp(0)/S
            const float lw = fminf(fmaxf((conf - 1.f/49.f) * (49.f/48.f), 0.f), 1.f);
            const int po = b * HWSZ + h * WDIM + w0 + sc * 16 + n;
            out[OFF_CONF + po] = conf;
            out[OFF_LW   + po] = lw;
            out[OFF_DY   + po] = sdy * invS;               // local; combine_k blends
            out[OFF_DX   + po] = sdx * invS;
        }
    }

    // ---- Global-branch logit sums: reduce over px lanes, LDS then global ----
#pragma unroll
    for (int m = 0; m < 13; ++m) {
        float v = tk[m];
        v += __shfl_xor(v, 1, 64); v += __shfl_xor(v, 2, 64);
        v += __shfl_xor(v, 4, 64); v += __shfl_xor(v, 8, 64);
        tk[m] = v;
    }
    if (n == 0) {
#pragma unroll
        for (int m = 0; m < 13; ++m) {
            const int k = g + 4 * m;
            if (k < 49) atomicAdd(&gacc_s[k], tk[m]);
        }
    }
    __syncthreads();
    if (tid < 49) atomicAdd(&ws[WS_GACC + b * 49 + tid], gacc_s[tid]);
}

__global__ void glob_branch_k(const float* __restrict__ ltemp,
                              float* __restrict__ out, float* __restrict__ ws)
{
    const int t = threadIdx.x;
    if (t >= 8) return;
    const float tau  = fmaxf(__expf(ltemp[0]), 1e-3f);
    const float itau = 1.f / tau;
    float tkk[49];
    float m = -1e30f;
#pragma unroll
    for (int k = 0; k < 49; ++k) {
        const float mean = ws[WS_GACC + t * 49 + k] * (1.f / 65536.f);
        tkk[k] = mean * itau;
        m = fmaxf(m, tkk[k]);
    }
    float S = 0.f, sdy = 0.f, sdx = 0.f;
#pragma unroll
    for (int k = 0; k < 49; ++k) {
        const float e = __expf(tkk[k] - m);
        S += e;
        sdy += e * (float)(k / 7 - 3);
        sdx += e * (float)(k % 7 - 3);
    }
    const float invS = 1.f / S;
    out[OFF_CG + t] = invS;                  // conf_global
    ws[WS_DYG + t] = sdy * invS;
    ws[WS_DXG + t] = sdx * invS;
}

__global__ void combine_k(float* __restrict__ out, const float* __restrict__ ws)
{
    const int gid = blockIdx.x * 256 + threadIdx.x;
    if (gid >= NPIX) return;
    const int b = gid >> 16;
    const float lw  = out[OFF_LW + gid];
    const float dyl = out[OFF_DY + gid];
    const float dxl = out[OFF_DX + gid];
    out[OFF_DY + gid] = lw * dyl + (1.f - lw) * ws[WS_DYG + b];
    out[OFF_DX + gid] = lw * dxl + (1.f - lw) * ws[WS_DXG + b];
}

extern "C" void kernel_launch(void* const* d_in, const int* in_sizes, int n_in,
                              void* d_out, int out_size, void* d_ws, size_t ws_size,
                              hipStream_t stream)
{
    const float* rub = (const float*)d_in[0];
    const float* vis = (const float*)d_in[1];
    const float* lt  = (const float*)d_in[2];
    float* out = (float*)d_out;
    float* ws  = (float*)d_ws;

    hipLaunchKernelGGL(zero_ws_k, dim3(1), dim3(512), 0, stream, ws);
    hipLaunchKernelGGL(corr_main_k, dim3(WDIM / TW, HDIM / TH, 8), dim3(BT), 0, stream,
                       rub, vis, lt, out, ws);
    hipLaunchKernelGGL(glob_branch_k, dim3(1), dim3(64), 0, stream, lt, out, ws);
    hipLaunchKernelGGL(combine_k, dim3(NPIX / 256), dim3(256), 0, stream, out, ws);
}